// Round 1
// 501.810 us; speedup vs baseline: 1.3298x; 1.3298x over previous
//
#include <hip/hip_runtime.h>
#include <cstdint>
#include <cstddef>

// Problem constants
#define OBS_DIMM 128
#define PROJJ    64
#define HIDD     256
#define LATT     24
#define BBATCH   1024
#define TTIME    256
#define NGATE    768   // 3*HID
#define MBLK     16    // batches per block
#define CHUNK    64    // timesteps per block
#define NGROUP   64
#define NCHUNK   4
#define HSTR     264   // h/mish row stride (ushorts): 256 + 8 pad (16B-aligned, bank-skewed)

using bf16x8 = __attribute__((ext_vector_type(8))) short;   // 8 bf16 in 4 VGPRs
using bf16x4 = __attribute__((ext_vector_type(4))) short;
using f32x4  = __attribute__((ext_vector_type(4))) float;

static __device__ __forceinline__ unsigned short f2bf(float f) {
    unsigned u = __builtin_bit_cast(unsigned, f);
    u += 0x7fffu + ((u >> 16) & 1u);          // RNE
    return (unsigned short)(u >> 16);
}
static __device__ __forceinline__ float bf2f(unsigned short h) {
    return __builtin_bit_cast(float, ((unsigned)h) << 16);
}
static __device__ __forceinline__ float fexp2(float x) { return __builtin_amdgcn_exp2f(x); }
static __device__ __forceinline__ float frcp (float x) { return __builtin_amdgcn_rcpf(x); }
static __device__ __forceinline__ float sigmoid_(float x) { return frcp(1.f + fexp2(-1.44269504f * x)); }
static __device__ __forceinline__ float tanh_(float x)    { return 1.f - 2.f * frcp(fexp2(2.88539008f * x) + 1.f); }
// mish(x) = x * tanh(softplus(x)) = x * (1 - 2/((1+e^x)^2 + 1))   [log-free identity]
static __device__ __forceinline__ unsigned short mish_bf(float x) {
    float ex = fexp2(1.44269504f * x);
    float t1 = 1.f + ex;
    return f2bf(x * (1.f - 2.f * frcp(t1 * t1 + 1.f)));
}

#define MFMA16(a, b, c) __builtin_amdgcn_mfma_f32_16x16x32_bf16((a), (b), (c), 0, 0, 0)

// ---------------------------------------------------------------------------
// Hidden-unit storage permutation: storage position p = 32w + 2c + i holds
// original unit U(p) = (2w+i)*16 + c.  This makes each thread's (i=0,i=1)
// pair adjacent in LDS -> paired b32 h/mish writes.  Consequences:
//   - W_hh rows and W_out rows are permuted in prep (k_store = perm_inv(k)).
//   - W_ih / W_in / gate-columns / biases are indexed by ORIGINAL unit ids
//     (column tiling (w,i,c16) unchanged).
//   - hx init / hfin write use U(p) explicitly in the GRU kernel.
// Fragment element: lane = q*16 + c16 holds k = kt*32 + q*8 + jj.
// ---------------------------------------------------------------------------
__global__ void prep_kernel(const float* __restrict__ W_in, const float* __restrict__ b_in,
                            const float* __restrict__ W_ih, const float* __restrict__ b_ih,
                            const float* __restrict__ W_hh, const float* __restrict__ W_out,
                            unsigned short* __restrict__ wsWhh, unsigned short* __restrict__ wsWih,
                            unsigned short* __restrict__ wsWin, unsigned short* __restrict__ wsWo,
                            float* __restrict__ wsBx) {
    int idx = blockIdx.x * 256 + threadIdx.x;
    if (idx < 196608) {                       // W_hh 256x768 (rows permuted)
        int k = idx / NGATE, n = idx - k * NGATE;
        int ks = ((k >> 5) << 5) | ((k & 15) << 1) | ((k >> 4) & 1);
        int kt = ks >> 5, q = (ks >> 3) & 3, jj = ks & 7;
        int g = n >> 8, u = n & 255, w = u >> 5, i = (u >> 4) & 1, c16 = u & 15;
        int lane = q * 16 + c16;
        wsWhh[((w * 8 + kt) * 6 + i * 3 + g) * 512 + lane * 8 + jj] = f2bf(W_hh[k * NGATE + n]);
    } else if (idx < 196608 + 49152) {        // W_ih 64x768 (x rows: no perm)
        int i2 = idx - 196608;
        int k = i2 / NGATE, n = i2 - k * NGATE;
        int kt = k >> 5, q = (k >> 3) & 3, jj = k & 7;
        int g = n >> 8, u = n & 255, w = u >> 5, i = (u >> 4) & 1, c16 = u & 15;
        int lane = q * 16 + c16;
        wsWih[((w * 2 + kt) * 6 + i * 3 + g) * 512 + lane * 8 + jj] = f2bf(W_ih[k * NGATE + n]);
    } else if (idx < 196608 + 49152 + 8192) { // W_in 128x64 (no perm)
        int i3 = idx - (196608 + 49152);
        int k = i3 >> 6, n = i3 & 63;
        int kt = k >> 5, q = (k >> 3) & 3, jj = k & 7;
        int nt = n >> 4, nl = n & 15;
        wsWin[(kt * 4 + nt) * 512 + (q * 16 + nl) * 8 + jj] = f2bf(W_in[k * PROJJ + n]);
    } else if (idx < 196608 + 49152 + 8192 + 8192) { // W_out 256x32 (rows permuted)
        int i4 = idx - (196608 + 49152 + 8192);
        int k = i4 >> 5, n = i4 & 31;
        float s = (n < LATT) ? W_out[k * LATT + n] : 0.f;
        int ks = ((k >> 5) << 5) | ((k & 15) << 1) | ((k >> 4) & 1);
        int kt = ks >> 5, q = (ks >> 3) & 3, jj = ks & 7;
        int nt = n >> 4, nl = n & 15;
        wsWo[(nt * 8 + kt) * 512 + (q * 16 + nl) * 8 + jj] = f2bf(s);
    } else if (idx < 196608 + 49152 + 8192 + 8192 + NGATE) {
        int n = idx - (196608 + 49152 + 8192 + 8192);
        float s = b_ih[n];
        for (int j = 0; j < PROJJ; ++j) s += b_in[j] * W_ih[j * NGATE + n];
        wsBx[n] = s;
    }
}

// ---------------------------------------------------------------------------
// x-projection pre-pass: x[b,t,:] = obs[b,t,:] @ W_in  (bias folded into wsBx).
// Output xf is stored directly in per-lane MFMA A-fragment layout:
//   xf[(g*256+t)*1024 + lane*16 + kt*8 + jj] = bf16(x[b=g*16+c16][k=kt*32+q*8+jj])
// so the recurrent kernel loads its x A-frags as two 16B coalesced reads.
// One wave per (g,t) tile; grid 4096 x 256 threads.
// ---------------------------------------------------------------------------
__global__ __launch_bounds__(256)
void xproj_kernel(const float* __restrict__ obs, const unsigned short* __restrict__ wsWin,
                  unsigned short* __restrict__ xf) {
    __shared__ __align__(16) unsigned short sXP[4][1040];
    const int tid = threadIdx.x, w = tid >> 6, lane = tid & 63, q = lane >> 4, c16 = lane & 15;
    const int tile = blockIdx.x * 4 + w;      // = g*256 + t
    const int g = tile >> 8, t = tile & 255;
    const float* op = obs + ((size_t)(g * 16 + c16) * TTIME + t) * OBS_DIMM + q * 8;
    bf16x8 a[4];
#pragma unroll
    for (int kt = 0; kt < 4; ++kt) {
        float4 u0 = *(const float4*)(op + kt * 32);
        float4 u1 = *(const float4*)(op + kt * 32 + 4);
        bf16x8 v;
        v[0] = (short)f2bf(u0.x); v[1] = (short)f2bf(u0.y);
        v[2] = (short)f2bf(u0.z); v[3] = (short)f2bf(u0.w);
        v[4] = (short)f2bf(u1.x); v[5] = (short)f2bf(u1.y);
        v[6] = (short)f2bf(u1.z); v[7] = (short)f2bf(u1.w);
        a[kt] = v;
    }
    f32x4 acc[4];
#pragma unroll
    for (int nt = 0; nt < 4; ++nt) acc[nt] = (f32x4){0.f, 0.f, 0.f, 0.f};
#pragma unroll
    for (int kt = 0; kt < 4; ++kt)
#pragma unroll
        for (int nt = 0; nt < 4; ++nt)
            acc[nt] = MFMA16(a[kt], *(const bf16x8*)(wsWin + (kt * 4 + nt) * 512 + lane * 8), acc[nt]);
    // scatter C (row=q*4+r, col=nt*16+c16) into A-frag layout, then coalesced flush
#pragma unroll
    for (int nt = 0; nt < 4; ++nt) {
        int unit = nt * 16 + c16;
        int ktp = unit >> 5, qp = (unit >> 3) & 3, jjp = unit & 7;
#pragma unroll
        for (int r = 0; r < 4; ++r)
            sXP[w][(qp * 16 + q * 4 + r) * 16 + ktp * 8 + jjp] = f2bf(acc[nt][r]);
    }
    __syncthreads();
    unsigned short* dst = xf + (size_t)tile * 1024 + lane * 16;
    *(bf16x8*)dst       = *(const bf16x8*)(sXP[w] + lane * 16);
    *(bf16x8*)(dst + 8) = *(const bf16x8*)(sXP[w] + lane * 16 + 8);
}

// ---------------------------------------------------------------------------
// Persistent-weight GRU: grid = 64 batch-groups x 4 time-chunks = 256 blocks.
// W_hh in VGPRs (48 frags, loaded once); W_ih/W_out in LDS; x pre-projected
// (xproj_kernel) and loaded as registers with 1-step prefetch.
// Steady state = 2 barriers/step:
//   G: acc-init(bias LDS) | x-part 12 MFMA (regs) | prefetch x(t+1), mask(t+1)
//      | h-part 48 MFMA (sH LDS A, reg B) | every other step waves 0-3: out-proj
//      MFMAs for t-2,t-1 from sM double buffer
//   barrier A
//   U: gates + h update + mish, paired b32 LDS writes; out-proj global stores
//   barrier B
// ---------------------------------------------------------------------------
__global__ __launch_bounds__(512, 2)
void gru_kernel(const int* __restrict__ is_init, const float* __restrict__ hx,
                const float* __restrict__ b_hh, const float* __restrict__ b_out,
                const unsigned short* __restrict__ wsWhh, const unsigned short* __restrict__ wsWih,
                const unsigned short* __restrict__ wsWo, const float* __restrict__ wsBx,
                const unsigned short* __restrict__ xf,
                float* __restrict__ out, float* __restrict__ hfin) {
    __shared__ __align__(16) unsigned short sWih[49152];        // 96 KB
    __shared__ __align__(16) unsigned short sWo[8192];          // 16 KB
    __shared__ __align__(16) unsigned short sH[MBLK * HSTR];    // h state bf16 (permuted units)
    __shared__ __align__(16) unsigned short sM[2][MBLK * HSTR]; // mish double buffer
    __shared__ __align__(16) float sBias[1056];                 // [gate*256+u] + [1024+outcol]
    __shared__ int sT;

    const int tid  = threadIdx.x;
    const int w    = tid >> 6;
    const int lane = tid & 63;
    const int q    = lane >> 4;
    const int c16  = lane & 15;
    const int bid  = blockIdx.x;
    const int g    = bid & (NGROUP - 1);
    const int ch   = bid >> 6;
    const int b0   = g * MBLK;
    const int t0   = ch * CHUNK;
    const int tend = t0 + CHUNK;

    // ---- persistent W_hh fragments: 48 x bf16x8 = 192 regs, loaded once ----
    const unsigned short* whh_p = wsWhh + (size_t)w * 24576 + lane * 8;
    bf16x8 Whh[48];
#pragma unroll
    for (int f = 0; f < 48; ++f)
        Whh[f] = *(const bf16x8*)(whh_p + (size_t)f * 512);

    // ---- stage W_ih' / W_out' into LDS (512 thr x 16B per iter) ----
    {
        const uint4* s1 = (const uint4*)wsWih; uint4* d1 = (uint4*)sWih;
#pragma unroll
        for (int r = 0; r < 12; ++r) d1[r * 512 + tid] = s1[r * 512 + tid];
        const uint4* s3 = (const uint4*)wsWo;  uint4* d3 = (uint4*)sWo;
#pragma unroll
        for (int r = 0; r < 2; ++r) d3[r * 512 + tid] = s3[r * 512 + tid];
    }
    // ---- biases to LDS (frees ~9 persistent VGPRs) ----
    if (tid < 256) {
        sBias[tid]       = wsBx[tid] + b_hh[tid];
        sBias[256 + tid] = wsBx[HIDD + tid] + b_hh[HIDD + tid];
        sBias[512 + tid] = wsBx[2 * HIDD + tid];
        sBias[768 + tid] = b_hh[2 * HIDD + tid];
    } else if (tid < 288) {
        int col = tid - 256;
        sBias[1024 + col] = (col < LATT) ? b_out[col] : 0.f;
    }
    if (tid == 0) sT = (ch == 0) ? 0 : 0x7fffffff;
    __syncthreads();

    // ---- find start time: most recent reset before t0 (min over group) ----
    if (ch > 0 && tid < MBLK) {
        int b = b0 + tid, fs = 0;
        for (int t = t0 - 1; t > 0; --t) {
            if (is_init[b * TTIME + t] != 0) { fs = t; break; }
        }
        atomicMin(&sT, fs);
    }
    __syncthreads();
    const int tstart = sT;

    // ---- init h (hx if tstart==0 else 0), masked at tstart; paired writes ----
    {
        int mloc = 0;
#pragma unroll
        for (int r = 0; r < 4; ++r)
            if (is_init[(b0 + q * 4 + r) * TTIME + tstart] != 0) mloc |= 1 << r;
#pragma unroll
        for (int r = 0; r < 4; ++r) {
            float h0v = 0.f, h1v = 0.f;
            if (tstart == 0 && !((mloc >> r) & 1)) {
                const float* hp = hx + (size_t)(b0 + q * 4 + r) * HIDD;
                h0v = hp[(2 * w) * 16 + c16];
                h1v = hp[(2 * w + 1) * 16 + c16];
            }
            ((unsigned*)sH)[(q * 4 + r) * 132 + w * 16 + c16] =
                (unsigned)f2bf(h0v) | ((unsigned)f2bf(h1v) << 16);
        }
    }
    // ---- prime x fragments for tstart ----
    bf16x8 X0, X1;
    {
        const unsigned short* xp = xf + (size_t)(g * 256 + tstart) * 1024 + lane * 16;
        X0 = *(const bf16x8*)xp; X1 = *(const bf16x8*)(xp + 8);
    }
    const unsigned short* wihp = sWih + w * 6144 + lane * 8;
    __syncthreads();

    for (int t = tstart; t < tend; ++t) {
        const bool emit = (t >= t0);
        // ---- phase G ----
        f32x4 accR[2], accZ[2], accXN[2], accHN[2];
#pragma unroll
        for (int i = 0; i < 2; ++i) {
            int u = (2 * w + i) * 16 + c16;
            float vR = sBias[u], vZ = sBias[256 + u], vX = sBias[512 + u], vH = sBias[768 + u];
            accR[i]  = (f32x4){vR, vR, vR, vR};
            accZ[i]  = (f32x4){vZ, vZ, vZ, vZ};
            accXN[i] = (f32x4){vX, vX, vX, vX};
            accHN[i] = (f32x4){vH, vH, vH, vH};
        }
        // x part first (consumes X0/X1 so the t+1 prefetch can reuse the regs)
#pragma unroll
        for (int i = 0; i < 2; ++i) {
            accR[i]  = MFMA16(X0, *(const bf16x8*)(wihp + (i * 3 + 0) * 512), accR[i]);
            accZ[i]  = MFMA16(X0, *(const bf16x8*)(wihp + (i * 3 + 1) * 512), accZ[i]);
            accXN[i] = MFMA16(X0, *(const bf16x8*)(wihp + (i * 3 + 2) * 512), accXN[i]);
            accR[i]  = MFMA16(X1, *(const bf16x8*)(wihp + (6 + i * 3 + 0) * 512), accR[i]);
            accZ[i]  = MFMA16(X1, *(const bf16x8*)(wihp + (6 + i * 3 + 1) * 512), accZ[i]);
            accXN[i] = MFMA16(X1, *(const bf16x8*)(wihp + (6 + i * 3 + 2) * 512), accXN[i]);
        }
        // prefetch x(t+1) + reset mask(t+1): ~2000cy of h-part MFMA ahead of the
        // pre-barrier vmcnt(0) drain -> HBM latency hidden
        {
            int tn = (t + 1 < TTIME) ? t + 1 : TTIME - 1;
            const unsigned short* xp = xf + (size_t)(g * 256 + tn) * 1024 + lane * 16;
            X0 = *(const bf16x8*)xp; X1 = *(const bf16x8*)(xp + 8);
        }
        int m4 = 0;
        if (t + 1 < tend) {
#pragma unroll
            for (int r = 0; r < 4; ++r)
                if (is_init[(b0 + q * 4 + r) * TTIME + t + 1] != 0) m4 |= 1 << r;
        }
        // h part: A from sH (LDS), B from registers
#pragma unroll
        for (int kt = 0; kt < 8; ++kt) {
            bf16x8 a = *(const bf16x8*)(sH + c16 * HSTR + kt * 32 + q * 8);
#pragma unroll
            for (int i = 0; i < 2; ++i) {
                accR[i]  = MFMA16(a, Whh[kt * 6 + i * 3 + 0], accR[i]);
                accZ[i]  = MFMA16(a, Whh[kt * 6 + i * 3 + 1], accZ[i]);
                accHN[i] = MFMA16(a, Whh[kt * 6 + i * 3 + 2], accHN[i]);
            }
        }
        // out-proj MFMAs for steps t-2 (sM[0]) and t-1 (sM[1]), waves 0-3,
        // every other step; sM reads complete before barrier A, stores after.
        f32x4 oa = (f32x4){0.f, 0.f, 0.f, 0.f};
        const bool doO = ((t & 1) == 0) && (t >= t0 + 2) && (w < 4);
        if (doO) {
            int nt = w & 1;
            float bo = sBias[1024 + nt * 16 + c16];
            oa = (f32x4){bo, bo, bo, bo};
            const unsigned short* smp = sM[w >> 1] + c16 * HSTR + q * 8;
#pragma unroll
            for (int kt = 0; kt < 8; ++kt)
                oa = MFMA16(*(const bf16x8*)(smp + kt * 32),
                            *(const bf16x8*)(sWo + (nt * 8 + kt) * 512 + lane * 8), oa);
        }
        __syncthreads();                       // A: sH/sM reads done before writes
        if (doO) {
            int nt = w & 1, col = nt * 16 + c16, tb = t - 2 + (w >> 1);
            if (col < LATT) {
#pragma unroll
                for (int r = 0; r < 4; ++r)
                    out[((size_t)(b0 + q * 4 + r) * TTIME + tb) * LATT + col] = oa[r];
            }
        }
        // ---- phase U: gates + h update (+ mish when emitting) ----
        const int par = t & 1;
#pragma unroll
        for (int r = 0; r < 4; ++r) {
            int bl = q * 4 + r;
            unsigned hpk = ((unsigned*)sH)[bl * 132 + w * 16 + c16];
            float hs0 = bf2f((unsigned short)(hpk & 0xffffu));
            float hs1 = bf2f((unsigned short)(hpk >> 16));
            float rr0 = sigmoid_(accR[0][r]), rr1 = sigmoid_(accR[1][r]);
            float zz0 = sigmoid_(accZ[0][r]), zz1 = sigmoid_(accZ[1][r]);
            float nn0 = tanh_(accXN[0][r] + rr0 * accHN[0][r]);
            float nn1 = tanh_(accXN[1][r] + rr1 * accHN[1][r]);
            float h0 = (1.f - zz0) * nn0 + zz0 * hs0;
            float h1 = (1.f - zz1) * nn1 + zz1 * hs1;
            if (emit)
                ((unsigned*)(sM[par]))[bl * 132 + w * 16 + c16] =
                    (unsigned)mish_bf(h0) | ((unsigned)mish_bf(h1) << 16);
            if ((m4 >> r) & 1) { h0 = 0.f; h1 = 0.f; }  // episode reset for t+1
            ((unsigned*)sH)[bl * 132 + w * 16 + c16] =
                (unsigned)f2bf(h0) | ((unsigned)f2bf(h1) << 16);
        }
        __syncthreads();                       // B: new h + mish visible
    }

    // ---- epilogue: out-proj for (tend-2, tend-1) ----
    if (w < 4) {
        int nt = w & 1;
        float bo = sBias[1024 + nt * 16 + c16];
        f32x4 oa = (f32x4){bo, bo, bo, bo};
        const unsigned short* smp = sM[w >> 1] + c16 * HSTR + q * 8;
#pragma unroll
        for (int kt = 0; kt < 8; ++kt)
            oa = MFMA16(*(const bf16x8*)(smp + kt * 32),
                        *(const bf16x8*)(sWo + (nt * 8 + kt) * 512 + lane * 8), oa);
        int col = nt * 16 + c16, tb = tend - 2 + (w >> 1);
        if (col < LATT) {
#pragma unroll
            for (int r = 0; r < 4; ++r)
                out[((size_t)(b0 + q * 4 + r) * TTIME + tb) * LATT + col] = oa[r];
        }
    }
    // ---- h_final from last chunk's blocks (unpermute) ----
    if (ch == NCHUNK - 1) {
#pragma unroll
        for (int r = 0; r < 4; ++r) {
            unsigned hpk = ((unsigned*)sH)[(q * 4 + r) * 132 + w * 16 + c16];
            float* hp = hfin + (size_t)(b0 + q * 4 + r) * HIDD;
            hp[(2 * w) * 16 + c16]     = bf2f((unsigned short)(hpk & 0xffffu));
            hp[(2 * w + 1) * 16 + c16] = bf2f((unsigned short)(hpk >> 16));
        }
    }
}

extern "C" void kernel_launch(void* const* d_in, const int* in_sizes, int n_in,
                              void* d_out, int out_size, void* d_ws, size_t ws_size,
                              hipStream_t stream) {
    const float* obs    = (const float*)d_in[0];
    const int*   isini  = (const int*)d_in[1];
    const float* hx     = (const float*)d_in[2];
    const float* W_in   = (const float*)d_in[3];
    const float* b_in   = (const float*)d_in[4];
    const float* W_ih   = (const float*)d_in[5];
    const float* b_ih   = (const float*)d_in[6];
    const float* W_hh   = (const float*)d_in[7];
    const float* b_hh   = (const float*)d_in[8];
    const float* W_out  = (const float*)d_in[9];
    const float* b_out  = (const float*)d_in[10];

    // workspace: xf (pre-projected x, bf16, fragment layout) | Whh' | Wih' |
    // Win' | Wo' | b_x   (~34.1 MB total)
    unsigned short* xfbuf = (unsigned short*)d_ws;              // 16777216 ushorts
    unsigned short* wsWhh = xfbuf + (size_t)BBATCH * TTIME * 64;
    unsigned short* wsWih = wsWhh + 196608;
    unsigned short* wsWin = wsWih + 49152;
    unsigned short* wsWo  = wsWin + 8192;
    float*          wsBx  = (float*)(wsWo + 8192);

    float* outp = (float*)d_out;
    float* hfin = outp + (size_t)BBATCH * TTIME * LATT;

    prep_kernel<<<1027, 256, 0, stream>>>(W_in, b_in, W_ih, b_ih, W_hh, W_out,
                                          wsWhh, wsWih, wsWin, wsWo, wsBx);
    xproj_kernel<<<4096, 256, 0, stream>>>(obs, wsWin, xfbuf);
    gru_kernel<<<256, 512, 0, stream>>>(isini, hx, b_hh, b_out,
                                        wsWhh, wsWih, wsWo, wsBx, xfbuf, outp, hfin);
}

// Round 2
// 491.389 us; speedup vs baseline: 1.3580x; 1.0212x over previous
//
#include <hip/hip_runtime.h>
#include <cstdint>
#include <cstddef>

// Problem constants
#define OBS_DIMM 128
#define PROJJ    64
#define HIDD     256
#define LATT     24
#define BBATCH   1024
#define TTIME    256
#define NGATE    768   // 3*HID
#define MBLK     16    // batches per block
#define CHUNK    64    // timesteps per block
#define NGROUP   64
#define NCHUNK   4
#define HSTR     264   // h/mish row stride (ushorts): 256 + 8 pad (16B-aligned, bank-skewed)

using bf16x8 = __attribute__((ext_vector_type(8))) short;   // 8 bf16 in 4 VGPRs
using bf16x4 = __attribute__((ext_vector_type(4))) short;
using f32x4  = __attribute__((ext_vector_type(4))) float;

static __device__ __forceinline__ unsigned short f2bf(float f) {
    unsigned u = __builtin_bit_cast(unsigned, f);
    u += 0x7fffu + ((u >> 16) & 1u);          // RNE
    return (unsigned short)(u >> 16);
}
static __device__ __forceinline__ float bf2f(unsigned short h) {
    return __builtin_bit_cast(float, ((unsigned)h) << 16);
}
static __device__ __forceinline__ float fexp2(float x) { return __builtin_amdgcn_exp2f(x); }
static __device__ __forceinline__ float frcp (float x) { return __builtin_amdgcn_rcpf(x); }
static __device__ __forceinline__ float sigmoid_(float x) { return frcp(1.f + fexp2(-1.44269504f * x)); }
static __device__ __forceinline__ float tanh_(float x)    { return 1.f - 2.f * frcp(fexp2(2.88539008f * x) + 1.f); }
// mish(x) = x * tanh(softplus(x)) = x * (1 - 2/((1+e^x)^2 + 1))   [log-free identity]
static __device__ __forceinline__ unsigned short mish_bf(float x) {
    float ex = fexp2(1.44269504f * x);
    float t1 = 1.f + ex;
    return f2bf(x * (1.f - 2.f * frcp(t1 * t1 + 1.f)));
}

// Fused barrier: drains LDS (cross-wave visibility of ds_writes) but leaves
// vmcnt outstanding -> xf prefetch stays in flight across the barrier (T4).
// Single opaque asm block: no IR/MIR pass can move memory ops across it.
static __device__ __forceinline__ void bar_lgkm() {
    asm volatile("s_waitcnt lgkmcnt(0)\n\ts_barrier" ::: "memory");
}

#define MFMA16(a, b, c) __builtin_amdgcn_mfma_f32_16x16x32_bf16((a), (b), (c), 0, 0, 0)

// ---------------------------------------------------------------------------
// Hidden-unit storage permutation: storage position p = 32w + 2c + i holds
// original unit U(p) = (2w+i)*16 + c  (paired b32 h/mish LDS traffic).
// W_hh / W_out rows permuted accordingly in prep; W_ih / W_in / biases use
// original unit ids.  Fragment element: lane = q*16 + c16 holds
// k = kt*32 + q*8 + jj.  prep is DEST-LINEAR: thread idx = dest offset,
// inverse-mapped to source -> coalesced 2B writes, cached scattered reads.
// Row perm within 32-block: ks5 = ((k&15)<<1)|((k>>4)&1); inverse
// k5 = ((s5&1)<<4)|(s5>>1).
// ---------------------------------------------------------------------------
__global__ void prep_kernel(const float* __restrict__ W_in, const float* __restrict__ b_in,
                            const float* __restrict__ W_ih, const float* __restrict__ b_ih,
                            const float* __restrict__ W_hh, const float* __restrict__ W_out,
                            unsigned short* __restrict__ wsWhh, unsigned short* __restrict__ wsWih,
                            unsigned short* __restrict__ wsWin, unsigned short* __restrict__ wsWo,
                            float* __restrict__ wsBx) {
    int idx = blockIdx.x * 256 + threadIdx.x;
    if (idx < 196608) {                       // W_hh 256x768 (rows permuted)
        int f = idx >> 9, rem = idx & 511, l = rem >> 3, jj = rem & 7;
        int q = l >> 4, c16 = l & 15;
        int g = f % 3, f2 = f / 3, i = f2 & 1, f3 = f2 >> 1;   // f3 = w*8+kt
        int kt = f3 & 7, w = f3 >> 3;
        int s5 = q * 8 + jj;
        int k = kt * 32 + ((s5 & 1) << 4) + (s5 >> 1);
        int n = g * 256 + (2 * w + i) * 16 + c16;
        wsWhh[idx] = f2bf(W_hh[k * NGATE + n]);
    } else if (idx < 245760) {                // W_ih 64x768 (x rows: no perm)
        int d = idx - 196608;
        int f = d >> 9, rem = d & 511, l = rem >> 3, jj = rem & 7;
        int q = l >> 4, c16 = l & 15;
        int g = f % 3, f2 = f / 3, i = f2 & 1, f3 = f2 >> 1;   // f3 = w*2+kt
        int kt = f3 & 1, w = f3 >> 1;
        int k = kt * 32 + q * 8 + jj;
        int n = g * 256 + (2 * w + i) * 16 + c16;
        wsWih[d] = f2bf(W_ih[k * NGATE + n]);
    } else if (idx < 253952) {                // W_in 128x64 (no perm)
        int d = idx - 245760;
        int f = d >> 9, rem = d & 511, l = rem >> 3, jj = rem & 7;
        int q = l >> 4, nl = l & 15;
        int nt = f & 3, kt = f >> 2;
        int k = kt * 32 + q * 8 + jj;
        int n = nt * 16 + nl;
        wsWin[d] = f2bf(W_in[k * PROJJ + n]);
    } else if (idx < 262144) {                // W_out 256x32 (rows permuted)
        int d = idx - 253952;
        int f = d >> 9, rem = d & 511, l = rem >> 3, jj = rem & 7;
        int q = l >> 4, nl = l & 15;
        int kt = f & 7, nt = f >> 3;
        int s5 = q * 8 + jj;
        int k = kt * 32 + ((s5 & 1) << 4) + (s5 >> 1);
        int n = nt * 16 + nl;
        wsWo[d] = f2bf((n < LATT) ? W_out[k * LATT + n] : 0.f);
    } else if (idx < 262912) {                // b_x = b_in @ W_ih + b_ih
        int n = idx - 262144;
        float s = b_ih[n];
        for (int j = 0; j < PROJJ; ++j) s += b_in[j] * W_ih[j * NGATE + n];
        wsBx[n] = s;
    }
}

// ---------------------------------------------------------------------------
// x-projection pre-pass: x[b,t,:] = obs[b,t,:] @ W_in  (bias folded into wsBx).
// Output xf stored in per-lane MFMA A-fragment layout:
//   xf[(g*256+t)*1024 + lane*16 + kt*8 + jj] = bf16(x[b=g*16+c16][k=kt*32+q*8+jj])
// ---------------------------------------------------------------------------
__global__ __launch_bounds__(256)
void xproj_kernel(const float* __restrict__ obs, const unsigned short* __restrict__ wsWin,
                  unsigned short* __restrict__ xf) {
    __shared__ __align__(16) unsigned short sXP[4][1040];
    const int tid = threadIdx.x, w = tid >> 6, lane = tid & 63, q = lane >> 4, c16 = lane & 15;
    const int tile = blockIdx.x * 4 + w;      // = g*256 + t
    const int g = tile >> 8, t = tile & 255;
    const float* op = obs + ((size_t)(g * 16 + c16) * TTIME + t) * OBS_DIMM + q * 8;
    bf16x8 a[4];
#pragma unroll
    for (int kt = 0; kt < 4; ++kt) {
        float4 u0 = *(const float4*)(op + kt * 32);
        float4 u1 = *(const float4*)(op + kt * 32 + 4);
        bf16x8 v;
        v[0] = (short)f2bf(u0.x); v[1] = (short)f2bf(u0.y);
        v[2] = (short)f2bf(u0.z); v[3] = (short)f2bf(u0.w);
        v[4] = (short)f2bf(u1.x); v[5] = (short)f2bf(u1.y);
        v[6] = (short)f2bf(u1.z); v[7] = (short)f2bf(u1.w);
        a[kt] = v;
    }
    f32x4 acc[4];
#pragma unroll
    for (int nt = 0; nt < 4; ++nt) acc[nt] = (f32x4){0.f, 0.f, 0.f, 0.f};
#pragma unroll
    for (int kt = 0; kt < 4; ++kt)
#pragma unroll
        for (int nt = 0; nt < 4; ++nt)
            acc[nt] = MFMA16(a[kt], *(const bf16x8*)(wsWin + (kt * 4 + nt) * 512 + lane * 8), acc[nt]);
    // scatter C (row=q*4+r, col=nt*16+c16) into A-frag layout, coalesced flush
#pragma unroll
    for (int nt = 0; nt < 4; ++nt) {
        int unit = nt * 16 + c16;
        int ktp = unit >> 5, qp = (unit >> 3) & 3, jjp = unit & 7;
#pragma unroll
        for (int r = 0; r < 4; ++r)
            sXP[w][(qp * 16 + q * 4 + r) * 16 + ktp * 8 + jjp] = f2bf(acc[nt][r]);
    }
    __syncthreads();
    unsigned short* dst = xf + (size_t)tile * 1024 + lane * 16;
    *(bf16x8*)dst       = *(const bf16x8*)(sXP[w] + lane * 16);
    *(bf16x8*)(dst + 8) = *(const bf16x8*)(sXP[w] + lane * 16 + 8);
}

// ---------------------------------------------------------------------------
// Persistent-weight GRU, ONE barrier per step.
// grid = 64 batch-groups x 4 time-chunks = 256 blocks x 512 thr.
// W_hh in regs (48 frags); W_ih/W_out in LDS; x pre-projected.
// Region t (between fused barriers):
//   prefetch xf(t+1) [global, crosses barrier un-drained]
//   h-part: 48 MFMA  (reads sH[read buf])
//   out-proj tb=t-2: 8 MFMA on one rotating wave-pair (reads sM[(t-2)%3])
//   m4(t+1) from sInit bitmask (LDS broadcast)
//   U: gates+h update from REGISTER hOld; writes sH[write buf], sM[t%3]
//   out stores (pair waves)
//   acc-init + x-part(t+1): 12 MFMA (sBias + sWih + prefetched X)
//   bar_lgkm(); swap sH bufs; rotate sM ptrs
// ---------------------------------------------------------------------------
__global__ __launch_bounds__(512, 2)
void gru_kernel(const int* __restrict__ is_init, const float* __restrict__ hx,
                const float* __restrict__ b_hh, const float* __restrict__ b_out,
                const unsigned short* __restrict__ wsWhh, const unsigned short* __restrict__ wsWih,
                const unsigned short* __restrict__ wsWo, const float* __restrict__ wsBx,
                const unsigned short* __restrict__ xf,
                float* __restrict__ out, float* __restrict__ hfin) {
    __shared__ __align__(16) unsigned short sWih[49152];          // 96 KB
    __shared__ __align__(16) unsigned short sWo[8192];            // 16 KB
    __shared__ __align__(16) unsigned short sH[2][MBLK * HSTR];   // h double buffer
    __shared__ __align__(16) unsigned short sM[3][MBLK * HSTR];   // mish triple buffer
    __shared__ __align__(16) float sBias[1056];                   // gates + out bias
    __shared__ unsigned sInit[MBLK][8];                           // is_init bitmask
    __shared__ int sT;

    const int tid  = threadIdx.x;
    const int w    = tid >> 6;
    const int lane = tid & 63;
    const int q    = lane >> 4;
    const int c16  = lane & 15;
    const int bid  = blockIdx.x;
    const int g    = bid & (NGROUP - 1);
    const int ch   = bid >> 6;
    const int b0   = g * MBLK;
    const int t0   = ch * CHUNK;
    const int tend = t0 + CHUNK;

    // ---- persistent W_hh fragments: 48 x bf16x8 = 192 regs, loaded once ----
    const unsigned short* whh_p = wsWhh + (size_t)w * 24576 + lane * 8;
    bf16x8 Whh[48];
#pragma unroll
    for (int f = 0; f < 48; ++f)
        Whh[f] = *(const bf16x8*)(whh_p + (size_t)f * 512);

    // ---- stage W_ih' / W_out' into LDS (512 thr x 16B per iter) ----
    {
        const uint4* s1 = (const uint4*)wsWih; uint4* d1 = (uint4*)sWih;
#pragma unroll
        for (int r = 0; r < 12; ++r) d1[r * 512 + tid] = s1[r * 512 + tid];
        const uint4* s3 = (const uint4*)wsWo;  uint4* d3 = (uint4*)sWo;
#pragma unroll
        for (int r = 0; r < 2; ++r) d3[r * 512 + tid] = s3[r * 512 + tid];
    }
    // ---- biases to LDS ----
    if (tid < 256) {
        sBias[tid]       = wsBx[tid] + b_hh[tid];
        sBias[256 + tid] = wsBx[HIDD + tid] + b_hh[HIDD + tid];
        sBias[512 + tid] = wsBx[2 * HIDD + tid];
        sBias[768 + tid] = b_hh[2 * HIDD + tid];
    } else if (tid < 288) {
        int col = tid - 256;
        sBias[1024 + col] = (col < LATT) ? b_out[col] : 0.f;
    }
    // ---- is_init bitmask: bit t of batch b ----
    if (tid < 128) {
        int b = tid >> 3, wd = tid & 7;
        unsigned m = 0;
        const int* ip = is_init + (size_t)(b0 + b) * TTIME + wd * 32;
#pragma unroll
        for (int j = 0; j < 32; ++j) m |= (ip[j] != 0 ? 1u : 0u) << j;
        sInit[b][wd] = m;
    }
    if (tid == 0) sT = (ch == 0) ? 0 : 0x7fffffff;
    __syncthreads();

    // ---- start time: most recent reset in [1, t0), min over group ----
    if (ch > 0 && tid < MBLK) {
        int fs = 0;
        for (int wi = (t0 >> 5) - 1; wi >= 0; --wi) {
            unsigned m = sInit[tid][wi];
            if (wi == 0) m &= ~1u;
            if (m) { fs = wi * 32 + 31 - __builtin_clz(m); break; }
        }
        atomicMin(&sT, fs);
    }
    __syncthreads();
    const int tstart = sT;

    // ---- init h (hx if tstart==0 && !reset, else 0); keep own pairs in regs ----
    unsigned hReg[4];
#pragma unroll
    for (int r = 0; r < 4; ++r) {
        int b = q * 4 + r;
        unsigned rbit = (sInit[b][tstart >> 5] >> (tstart & 31)) & 1u;
        float h0v = 0.f, h1v = 0.f;
        if (tstart == 0 && !rbit) {
            const float* hp = hx + (size_t)(b0 + b) * HIDD;
            h0v = hp[2 * w * 16 + c16];
            h1v = hp[(2 * w + 1) * 16 + c16];
        }
        unsigned pk = (unsigned)f2bf(h0v) | ((unsigned)f2bf(h1v) << 16);
        hReg[r] = pk;
        ((unsigned*)sH[0])[b * 132 + w * 16 + c16] = pk;
    }
    // ---- prime x fragments for tstart ----
    bf16x8 X0, X1;
    {
        const unsigned short* xp = xf + (size_t)(g * 256 + tstart) * 1024 + lane * 16;
        X0 = *(const bf16x8*)xp; X1 = *(const bf16x8*)(xp + 8);
    }
    const unsigned short* wihp = sWih + w * 6144 + lane * 8;
    unsigned short* sHr = sH[0];
    unsigned short* sHw = sH[1];
    unsigned short* pWm = sM[tstart % 3];
    unsigned short* pR1 = sM[(tstart + 2) % 3];   // (t-1)%3
    unsigned short* pR2 = sM[(tstart + 1) % 3];   // (t-2)%3
    __syncthreads();

    f32x4 accR[2], accZ[2], accXN[2], accHN[2];
    auto accfill = [&]() {                        // bias + x-part (12 MFMA)
#pragma unroll
        for (int i = 0; i < 2; ++i) {
            int u = (2 * w + i) * 16 + c16;
            float vR = sBias[u], vZ = sBias[256 + u], vX = sBias[512 + u], vH = sBias[768 + u];
            accR[i]  = (f32x4){vR, vR, vR, vR};
            accZ[i]  = (f32x4){vZ, vZ, vZ, vZ};
            accXN[i] = (f32x4){vX, vX, vX, vX};
            accHN[i] = (f32x4){vH, vH, vH, vH};
            accR[i]  = MFMA16(X0, *(const bf16x8*)(wihp + (i * 3 + 0) * 512), accR[i]);
            accZ[i]  = MFMA16(X0, *(const bf16x8*)(wihp + (i * 3 + 1) * 512), accZ[i]);
            accXN[i] = MFMA16(X0, *(const bf16x8*)(wihp + (i * 3 + 2) * 512), accXN[i]);
            accR[i]  = MFMA16(X1, *(const bf16x8*)(wihp + (6 + i * 3 + 0) * 512), accR[i]);
            accZ[i]  = MFMA16(X1, *(const bf16x8*)(wihp + (6 + i * 3 + 1) * 512), accZ[i]);
            accXN[i] = MFMA16(X1, *(const bf16x8*)(wihp + (6 + i * 3 + 2) * 512), accXN[i]);
        }
    };
    accfill();                                    // for tstart

    for (int t = tstart; t < tend; ++t) {
        // ---- prefetch x(t+1): stays in flight across the fused barrier ----
        {
            int tn = (t + 1 < TTIME) ? t + 1 : TTIME - 1;
            const unsigned short* xp = xf + (size_t)(g * 256 + tn) * 1024 + lane * 16;
            X0 = *(const bf16x8*)xp; X1 = *(const bf16x8*)(xp + 8);
        }
        // ---- h-part: A from sH (LDS), B from registers (48 MFMA) ----
#pragma unroll
        for (int kt = 0; kt < 8; ++kt) {
            bf16x8 a = *(const bf16x8*)(sHr + c16 * HSTR + kt * 32 + q * 8);
#pragma unroll
            for (int i = 0; i < 2; ++i) {
                accR[i]  = MFMA16(a, Whh[kt * 6 + i * 3 + 0], accR[i]);
                accZ[i]  = MFMA16(a, Whh[kt * 6 + i * 3 + 1], accZ[i]);
                accHN[i] = MFMA16(a, Whh[kt * 6 + i * 3 + 2], accHN[i]);
            }
        }
        // ---- out-proj tb = t-2 on rotating wave pair ----
        f32x4 oa;
        const bool doO = (t >= t0 + 2) && ((w >> 1) == (t & 3));
        if (doO) {
            int nt = w & 1;
            float bo = sBias[1024 + nt * 16 + c16];
            oa = (f32x4){bo, bo, bo, bo};
            const unsigned short* smp = pR2 + c16 * HSTR + q * 8;
#pragma unroll
            for (int kt = 0; kt < 8; ++kt)
                oa = MFMA16(*(const bf16x8*)(smp + kt * 32),
                            *(const bf16x8*)(sWo + (nt * 8 + kt) * 512 + lane * 8), oa);
        }
        // ---- reset mask for t+1 from bitmask (broadcast LDS reads) ----
        int m4 = 0;
        if (t + 1 < tend) {
            int wd = (t + 1) >> 5, bt = (t + 1) & 31;
#pragma unroll
            for (int r = 0; r < 4; ++r)
                m4 |= (int)((sInit[q * 4 + r][wd] >> bt) & 1u) << r;
        }
        // ---- U: gates + h update (hOld from registers) ----
        const bool emit = (t >= t0);
#pragma unroll
        for (int r = 0; r < 4; ++r) {
            int bl = q * 4 + r;
            float hs0 = bf2f((unsigned short)(hReg[r] & 0xffffu));
            float hs1 = bf2f((unsigned short)(hReg[r] >> 16));
            float rr0 = sigmoid_(accR[0][r]), rr1 = sigmoid_(accR[1][r]);
            float zz0 = sigmoid_(accZ[0][r]), zz1 = sigmoid_(accZ[1][r]);
            float nn0 = tanh_(accXN[0][r] + rr0 * accHN[0][r]);
            float nn1 = tanh_(accXN[1][r] + rr1 * accHN[1][r]);
            float h0 = (1.f - zz0) * nn0 + zz0 * hs0;
            float h1 = (1.f - zz1) * nn1 + zz1 * hs1;
            if (emit)
                ((unsigned*)pWm)[bl * 132 + w * 16 + c16] =
                    (unsigned)mish_bf(h0) | ((unsigned)mish_bf(h1) << 16);
            if ((m4 >> r) & 1) { h0 = 0.f; h1 = 0.f; }   // episode reset for t+1
            unsigned pk = (unsigned)f2bf(h0) | ((unsigned)f2bf(h1) << 16);
            hReg[r] = pk;
            ((unsigned*)sHw)[bl * 132 + w * 16 + c16] = pk;
        }
        // ---- out stores (pair waves; un-waited, drains lazily) ----
        if (doO) {
            int nt = w & 1, col = nt * 16 + c16, tb = t - 2;
            if (col < LATT) {
#pragma unroll
                for (int r = 0; r < 4; ++r)
                    out[((size_t)(b0 + q * 4 + r) * TTIME + tb) * LATT + col] = oa[r];
            }
        }
        // ---- next-step bias + x-part (12 MFMA, consumes prefetched X) ----
        if (t + 1 < tend) accfill();
        bar_lgkm();
        { unsigned short* tp = sHr; sHr = sHw; sHw = tp; }
        { unsigned short* tp = pWm; pWm = pR2; pR2 = pR1; pR1 = tp; }
    }

    // ---- epilogue out-proj: tend-2 (waves 0,1) and tend-1 (waves 2,3) ----
    if (w < 4) {
        int nt = w & 1;
        unsigned short* pR = (w < 2) ? pR2 : pR1;
        int tb = (w < 2) ? tend - 2 : tend - 1;
        float bo = sBias[1024 + nt * 16 + c16];
        f32x4 oa2 = (f32x4){bo, bo, bo, bo};
        const unsigned short* smp = pR + c16 * HSTR + q * 8;
#pragma unroll
        for (int kt = 0; kt < 8; ++kt)
            oa2 = MFMA16(*(const bf16x8*)(smp + kt * 32),
                         *(const bf16x8*)(sWo + (nt * 8 + kt) * 512 + lane * 8), oa2);
        int col = nt * 16 + c16;
        if (col < LATT) {
#pragma unroll
            for (int r = 0; r < 4; ++r)
                out[((size_t)(b0 + q * 4 + r) * TTIME + tb) * LATT + col] = oa2[r];
        }
    }
    // ---- h_final straight from registers (each thread owns its pairs) ----
    if (ch == NCHUNK - 1) {
#pragma unroll
        for (int r = 0; r < 4; ++r) {
            float* hp = hfin + (size_t)(b0 + q * 4 + r) * HIDD;
            hp[2 * w * 16 + c16]       = bf2f((unsigned short)(hReg[r] & 0xffffu));
            hp[(2 * w + 1) * 16 + c16] = bf2f((unsigned short)(hReg[r] >> 16));
        }
    }
}

extern "C" void kernel_launch(void* const* d_in, const int* in_sizes, int n_in,
                              void* d_out, int out_size, void* d_ws, size_t ws_size,
                              hipStream_t stream) {
    const float* obs    = (const float*)d_in[0];
    const int*   isini  = (const int*)d_in[1];
    const float* hx     = (const float*)d_in[2];
    const float* W_in   = (const float*)d_in[3];
    const float* b_in   = (const float*)d_in[4];
    const float* W_ih   = (const float*)d_in[5];
    const float* b_ih   = (const float*)d_in[6];
    const float* W_hh   = (const float*)d_in[7];
    const float* b_hh   = (const float*)d_in[8];
    const float* W_out  = (const float*)d_in[9];
    const float* b_out  = (const float*)d_in[10];

    // workspace: xf (pre-projected x, bf16, fragment layout) | Whh' | Wih' |
    // Win' | Wo' | b_x   (~34.1 MB total)
    unsigned short* xfbuf = (unsigned short*)d_ws;              // 16777216 ushorts
    unsigned short* wsWhh = xfbuf + (size_t)BBATCH * TTIME * 64;
    unsigned short* wsWih = wsWhh + 196608;
    unsigned short* wsWin = wsWih + 49152;
    unsigned short* wsWo  = wsWin + 8192;
    float*          wsBx  = (float*)(wsWo + 8192);

    float* outp = (float*)d_out;
    float* hfin = outp + (size_t)BBATCH * TTIME * LATT;

    prep_kernel<<<1027, 256, 0, stream>>>(W_in, b_in, W_ih, b_ih, W_hh, W_out,
                                          wsWhh, wsWih, wsWin, wsWo, wsBx);
    xproj_kernel<<<4096, 256, 0, stream>>>(obs, wsWin, xfbuf);
    gru_kernel<<<256, 512, 0, stream>>>(isini, hx, b_hh, b_out,
                                        wsWhh, wsWih, wsWo, wsBx, xfbuf, outp, hfin);
}